// Round 4
// baseline (147.845 us; speedup 1.0000x reference)
//
#include <hip/hip_runtime.h>
#include <cfloat>
#include <math.h>
#include <stdint.h>

// Match XLA-CPU f32 arithmetic exactly: no implicit contraction anywhere;
// FMA only where written explicitly (Eigen-gemm-style cross product).
#pragma clang fp contract(off)

#define RPW 16    // receivers per block (quarter of B=64)
#define NQ  512   // tile phases per receiver-quarter; grid = 4*NQ = 2048

__device__ __forceinline__ uint32_t monotone_key(float f) {
    uint32_t u = __float_as_uint(f);
    return (u & 0x80000000u) ? ~u : (u | 0x80000000u);
}

// force a wave-uniform float into an SGPR
__device__ __forceinline__ float rfl_f(float x) {
    return __uint_as_float((uint32_t)__builtin_amdgcn_readfirstlane((int)__float_as_uint(x)));
}

__device__ __forceinline__ unsigned long long shfl_xor_u64(unsigned long long v, int m) {
    uint32_t lo = (uint32_t)v, hi = (uint32_t)(v >> 32);
    lo = (uint32_t)__shfl_xor((int)lo, m, 64);
    hi = (uint32_t)__shfl_xor((int)hi, m, 64);
    return ((unsigned long long)hi << 32) | lo;
}

// lane = point; 16 receivers per block live in SGPRs -> inner loop is pure
// VALU (8 ops/pair-eval). LDS ~512B so occupancy is VGPR-bound: 8 waves/SIMD.
__global__ void __launch_bounds__(256, 8) fused_kernel(
        const float* __restrict__ mesh, const float* __restrict__ recv,
        float* __restrict__ out, unsigned long long* __restrict__ ws,
        int L, int B, int ntiles) {
    __shared__ unsigned long long wmin[4][RPW];

    const int tid  = threadIdx.x;
    const int lane = tid & 63;
    const int wave = tid >> 6;
    const int rq   = blockIdx.x / NQ;      // receiver quarter 0..3
    const int q0   = blockIdx.x % NQ;      // starting tile phase

    // ---- receiver set into SGPRs (once) ----
    float rx[RPW], ry[RPW], rz[RPW], rsq[RPW];
#pragma unroll
    for (int c = 0; c < RPW; ++c) {
        const int r = rq * RPW + c;
        float x = 0.f, y = 0.f, z = 0.f;
        if (r < B) {                       // uniform branch
            x = recv[r * 3 + 0];
            y = recv[r * 3 + 1];
            z = recv[r * 3 + 2];
        }
        rx[c]  = rfl_f(x);
        ry[c]  = rfl_f(y);
        rz[c]  = rfl_f(z);
        rsq[c] = rfl_f((x * x + y * y) + z * z);   // no FMA (pragma)
    }

    float best[RPW];
    int   bidx[RPW];
#pragma unroll
    for (int c = 0; c < RPW; ++c) { best[c] = FLT_MAX; bidx[c] = 0x7fffffff; }

    // one pair-eval against all 16 receivers (pure VALU, 8 ops/pair)
    auto eval_point = [&](float x, float y, float z, int gidx) {
        const float ms = (x * x + y * y) + z * z;   // matches jnp.sum(m*m): no FMA
#pragma unroll
        for (int c = 0; c < RPW; ++c) {
            float cr = fmaf(rz[c], z, fmaf(ry[c], y, rx[c] * x));  // Eigen K-asc
            float d2 = fmaf(-2.0f, cr, ms) + rsq[c];
            if (d2 < best[c]) { best[c] = d2; bidx[c] = gidx; }    // strict <
        }
    };

    for (int t = q0; t < ntiles; t += NQ) {
        const int p0 = (t << 10) + (wave << 8) + (lane << 2);   // lane's 4 points
        if (p0 + 4 <= L) {
            const float4* __restrict__ m4 = (const float4*)(mesh + (size_t)p0 * 3);
            const float4 fa = m4[0], fb = m4[1], fc = m4[2];
            if ((t & 3) == rq) {           // rotated writer: spread stores evenly
                float4* __restrict__ o4 = (float4*)(out + (size_t)p0 * 4);
                o4[0] = make_float4(fa.x, fa.y, fa.z, 0.f);
                o4[1] = make_float4(fa.w, fb.x, fb.y, 0.f);
                o4[2] = make_float4(fb.z, fb.w, fc.x, 0.f);
                o4[3] = make_float4(fc.y, fc.z, fc.w, 0.f);
            }
            eval_point(fa.x, fa.y, fa.z, p0 + 0);
            eval_point(fa.w, fb.x, fb.y, p0 + 1);
            eval_point(fb.z, fb.w, fc.x, p0 + 2);
            eval_point(fc.y, fc.z, fc.w, p0 + 3);
        } else {
            for (int j = 0; j < 4; ++j) {
                const int p = p0 + j;
                if (p >= L) break;
                const float x = mesh[(size_t)p * 3 + 0];
                const float y = mesh[(size_t)p * 3 + 1];
                const float z = mesh[(size_t)p * 3 + 2];
                if ((t & 3) == rq) {
                    out[(size_t)p * 4 + 0] = x;
                    out[(size_t)p * 4 + 1] = y;
                    out[(size_t)p * 4 + 2] = z;
                    out[(size_t)p * 4 + 3] = 0.f;
                }
                eval_point(x, y, z, p);
            }
        }
    }

    // ---- per-wave butterfly reduce on packed (key|idx), then tiny LDS fold ----
#pragma unroll
    for (int c = 0; c < RPW; ++c) {
        unsigned long long k =
            ((unsigned long long)monotone_key(best[c]) << 32) | (unsigned int)bidx[c];
#pragma unroll
        for (int off = 32; off >= 1; off >>= 1) {
            unsigned long long o = shfl_xor_u64(k, off);
            if (o < k) k = o;
        }
        if (lane == 0) wmin[wave][c] = k;
    }
    __syncthreads();
    if (tid < RPW) {
        unsigned long long k = wmin[0][tid];
#pragma unroll
        for (int w = 1; w < 4; ++w) {
            unsigned long long o = wmin[w][tid];
            if (o < k) k = o;
        }
        const int r = rq * RPW + tid;
        if (r < B) atomicMin(&ws[r], k);
    }
}

// scatter one-hot 1.0s and emit closest_points
__global__ void finalize_kernel(
        const float* __restrict__ mesh, const unsigned long long* __restrict__ ws,
        float* __restrict__ out, int L, int B) {
    const int r = threadIdx.x;
    if (r >= B) return;
    const int idx = (int)(ws[r] & 0xFFFFFFFFull);
    out[(size_t)idx * 4 + 3] = 1.0f;
    float* cp = out + (size_t)L * 4 + (size_t)r * 3;
    cp[0] = mesh[(size_t)idx * 3 + 0];
    cp[1] = mesh[(size_t)idx * 3 + 1];
    cp[2] = mesh[(size_t)idx * 3 + 2];
}

extern "C" void kernel_launch(void* const* d_in, const int* in_sizes, int n_in,
                              void* d_out, int out_size, void* d_ws, size_t ws_size,
                              hipStream_t stream) {
    const float* mesh = (const float*)d_in[0];
    const float* recv = (const float*)d_in[1];
    float* out = (float*)d_out;
    const int L = in_sizes[0] / 3;
    const int B = in_sizes[1] / 3;   // 64
    unsigned long long* ws = (unsigned long long*)d_ws;

    // init per-receiver packed (key|idx) mins to all-ones (max)
    hipMemsetAsync(ws, 0xFF, (size_t)B * sizeof(unsigned long long), stream);

    const int ntiles = (L + 1023) / 1024;
    fused_kernel<<<4 * NQ, 256, 0, stream>>>(mesh, recv, out, ws, L, B, ntiles);

    finalize_kernel<<<1, 64, 0, stream>>>(mesh, ws, out, L, B);
}

// Round 5
// 89.428 us; speedup vs baseline: 1.6532x; 1.6532x over previous
//
#include <hip/hip_runtime.h>
#include <cfloat>
#include <math.h>
#include <stdint.h>

// Match XLA-CPU f32 arithmetic exactly: no implicit contraction anywhere;
// FMA only where written explicitly (Eigen-gemm-style cross product).
#pragma clang fp contract(off)

#define RPW 16    // receivers per block (quarter of B=64)
#define NQ  512   // tile phases per receiver-quarter; grid = 4*NQ = 2048

__device__ __forceinline__ uint32_t monotone_key(float f) {
    uint32_t u = __float_as_uint(f);
    return (u & 0x80000000u) ? ~u : (u | 0x80000000u);
}

// force a wave-uniform float into an SGPR
__device__ __forceinline__ float rfl_f(float x) {
    return __uint_as_float((uint32_t)__builtin_amdgcn_readfirstlane((int)__float_as_uint(x)));
}

__device__ __forceinline__ unsigned long long shfl_xor_u64(unsigned long long v, int m) {
    uint32_t lo = (uint32_t)v, hi = (uint32_t)(v >> 32);
    lo = (uint32_t)__shfl_xor((int)lo, m, 64);
    hi = (uint32_t)__shfl_xor((int)hi, m, 64);
    return ((unsigned long long)hi << 32) | lo;
}

// lane = point; 16 receivers per block live in SGPRs -> inner loop is pure
// VALU (8 ops/pair-eval). LDS ~512B; VGPR target <=64 -> 8 waves/SIMD.
// launch_bounds(256,4): cap 128 VGPRs — do NOT squeeze the allocator (r4:
// (256,8) forced VGPR=32 and spilled best[]/bidx[] to scratch, +600MB HBM).
__global__ void __launch_bounds__(256, 4) fused_kernel(
        const float* __restrict__ mesh, const float* __restrict__ recv,
        float* __restrict__ out, unsigned long long* __restrict__ ws,
        int L, int B, int ntiles) {
    __shared__ unsigned long long wmin[4][RPW];

    const int tid  = threadIdx.x;
    const int lane = tid & 63;
    const int wave = tid >> 6;
    const int rq   = blockIdx.x / NQ;      // receiver quarter 0..3
    const int q0   = blockIdx.x % NQ;      // starting tile phase

    // ---- receiver set into SGPRs (once) ----
    float rx[RPW], ry[RPW], rz[RPW], rsq[RPW];
#pragma unroll
    for (int c = 0; c < RPW; ++c) {
        const int r = rq * RPW + c;
        float x = 0.f, y = 0.f, z = 0.f;
        if (r < B) {                       // uniform branch
            x = recv[r * 3 + 0];
            y = recv[r * 3 + 1];
            z = recv[r * 3 + 2];
        }
        rx[c]  = rfl_f(x);
        ry[c]  = rfl_f(y);
        rz[c]  = rfl_f(z);
        rsq[c] = rfl_f((x * x + y * y) + z * z);   // no FMA (pragma)
    }

    float best[RPW];
    int   bidx[RPW];
#pragma unroll
    for (int c = 0; c < RPW; ++c) { best[c] = FLT_MAX; bidx[c] = 0x7fffffff; }

    // one pair-eval against all 16 receivers (pure VALU, 8 ops/pair)
    auto eval_point = [&](float x, float y, float z, int gidx) {
        const float ms = (x * x + y * y) + z * z;   // matches jnp.sum(m*m): no FMA
#pragma unroll
        for (int c = 0; c < RPW; ++c) {
            float cr = fmaf(rz[c], z, fmaf(ry[c], y, rx[c] * x));  // Eigen K-asc
            float d2 = fmaf(-2.0f, cr, ms) + rsq[c];
            if (d2 < best[c]) { best[c] = d2; bidx[c] = gidx; }    // strict <
        }
    };

    int k = 0;                             // tile-iteration counter
    for (int t = q0; t < ntiles; t += NQ, ++k) {
        const int p0 = (t << 10) + (wave << 8) + (lane << 2);   // lane's 4 points
        const bool writer = (((q0 + k) & 3) == rq);   // balanced: 1 writer/tile
        if (p0 + 4 <= L) {
            const float4* __restrict__ m4 = (const float4*)(mesh + (size_t)p0 * 3);
            const float4 fa = m4[0], fb = m4[1], fc = m4[2];
            if (writer) {
                float4* __restrict__ o4 = (float4*)(out + (size_t)p0 * 4);
                o4[0] = make_float4(fa.x, fa.y, fa.z, 0.f);
                o4[1] = make_float4(fa.w, fb.x, fb.y, 0.f);
                o4[2] = make_float4(fb.z, fb.w, fc.x, 0.f);
                o4[3] = make_float4(fc.y, fc.z, fc.w, 0.f);
            }
            eval_point(fa.x, fa.y, fa.z, p0 + 0);
            eval_point(fa.w, fb.x, fb.y, p0 + 1);
            eval_point(fb.z, fb.w, fc.x, p0 + 2);
            eval_point(fc.y, fc.z, fc.w, p0 + 3);
        } else {
            for (int j = 0; j < 4; ++j) {
                const int p = p0 + j;
                if (p >= L) break;
                const float x = mesh[(size_t)p * 3 + 0];
                const float y = mesh[(size_t)p * 3 + 1];
                const float z = mesh[(size_t)p * 3 + 2];
                if (writer) {
                    out[(size_t)p * 4 + 0] = x;
                    out[(size_t)p * 4 + 1] = y;
                    out[(size_t)p * 4 + 2] = z;
                    out[(size_t)p * 4 + 3] = 0.f;
                }
                eval_point(x, y, z, p);
            }
        }
    }

    // ---- per-wave butterfly reduce on packed (key|idx), then tiny LDS fold ----
#pragma unroll
    for (int c = 0; c < RPW; ++c) {
        unsigned long long kk =
            ((unsigned long long)monotone_key(best[c]) << 32) | (unsigned int)bidx[c];
#pragma unroll
        for (int off = 32; off >= 1; off >>= 1) {
            unsigned long long o = shfl_xor_u64(kk, off);
            if (o < kk) kk = o;
        }
        if (lane == 0) wmin[wave][c] = kk;
    }
    __syncthreads();
    if (tid < RPW) {
        unsigned long long kk = wmin[0][tid];
#pragma unroll
        for (int w = 1; w < 4; ++w) {
            unsigned long long o = wmin[w][tid];
            if (o < kk) kk = o;
        }
        const int r = rq * RPW + tid;
        if (r < B) atomicMin(&ws[r], kk);
    }
}

// scatter one-hot 1.0s and emit closest_points
__global__ void finalize_kernel(
        const float* __restrict__ mesh, const unsigned long long* __restrict__ ws,
        float* __restrict__ out, int L, int B) {
    const int r = threadIdx.x;
    if (r >= B) return;
    const int idx = (int)(ws[r] & 0xFFFFFFFFull);
    out[(size_t)idx * 4 + 3] = 1.0f;
    float* cp = out + (size_t)L * 4 + (size_t)r * 3;
    cp[0] = mesh[(size_t)idx * 3 + 0];
    cp[1] = mesh[(size_t)idx * 3 + 1];
    cp[2] = mesh[(size_t)idx * 3 + 2];
}

extern "C" void kernel_launch(void* const* d_in, const int* in_sizes, int n_in,
                              void* d_out, int out_size, void* d_ws, size_t ws_size,
                              hipStream_t stream) {
    const float* mesh = (const float*)d_in[0];
    const float* recv = (const float*)d_in[1];
    float* out = (float*)d_out;
    const int L = in_sizes[0] / 3;
    const int B = in_sizes[1] / 3;   // 64
    unsigned long long* ws = (unsigned long long*)d_ws;

    // init per-receiver packed (key|idx) mins to all-ones (max)
    hipMemsetAsync(ws, 0xFF, (size_t)B * sizeof(unsigned long long), stream);

    const int ntiles = (L + 1023) / 1024;
    fused_kernel<<<4 * NQ, 256, 0, stream>>>(mesh, recv, out, ws, L, B, ntiles);

    finalize_kernel<<<1, 64, 0, stream>>>(mesh, ws, out, L, B);
}

// Round 6
// 87.499 us; speedup vs baseline: 1.6897x; 1.0220x over previous
//
#include <hip/hip_runtime.h>
#include <cfloat>
#include <math.h>
#include <stdint.h>

// Match XLA-CPU f32 arithmetic exactly: no implicit contraction anywhere;
// FMA only where written explicitly (Eigen-gemm-style cross product).
#pragma clang fp contract(off)

#define RPW    16    // receivers per block (quarter of B=64)
#define NPHASE 256   // tile phases per (quarter, half)
#define NHALF  2     // tile-range halves; grid = 4 * NHALF * NPHASE = 2048 = 256CU x 8

__device__ __forceinline__ uint32_t monotone_key(float f) {
    uint32_t u = __float_as_uint(f);
    return (u & 0x80000000u) ? ~u : (u | 0x80000000u);
}

// force a wave-uniform float into an SGPR
__device__ __forceinline__ float rfl_f(float x) {
    return __uint_as_float((uint32_t)__builtin_amdgcn_readfirstlane((int)__float_as_uint(x)));
}

__device__ __forceinline__ unsigned long long shfl_xor_u64(unsigned long long v, int m) {
    uint32_t lo = (uint32_t)v, hi = (uint32_t)(v >> 32);
    lo = (uint32_t)__shfl_xor((int)lo, m, 64);
    hi = (uint32_t)__shfl_xor((int)hi, m, 64);
    return ((unsigned long long)hi << 32) | lo;
}

// lane = point; 16 receivers per block live in SGPRs -> inner loop is pure
// VALU (8 ops/pair-eval). LDS 512B, VGPR ~52 -> HW allows 8 blocks/CU; grid
// 2048 fills the machine exactly so all quarter-partners are co-resident
// (L2 co-walking) and prologue overlaps machine-wide.
// launch_bounds(256,4): cap 128 VGPRs — do NOT squeeze the allocator (r4:
// (256,8) forced VGPR=32 and spilled best[]/bidx[] to scratch, +600MB HBM).
__global__ void __launch_bounds__(256, 4) fused_kernel(
        const float* __restrict__ mesh, const float* __restrict__ recv,
        float* __restrict__ out, unsigned long long* __restrict__ ws,
        int L, int B, int ntiles) {
    __shared__ unsigned long long wmin[4][RPW];

    const int tid  = threadIdx.x;
    const int lane = tid & 63;
    const int wave = tid >> 6;
    const int rq   = blockIdx.x >> 9;        // receiver quarter 0..3
    const int rem  = blockIdx.x & 511;
    const int hf   = rem >> 8;               // tile-range half 0..1
    const int q0   = rem & 255;              // tile phase within half

    // ---- receiver set into SGPRs (once) ----
    float rx[RPW], ry[RPW], rz[RPW], rsq[RPW];
#pragma unroll
    for (int c = 0; c < RPW; ++c) {
        const int r = rq * RPW + c;
        float x = 0.f, y = 0.f, z = 0.f;
        if (r < B) {                         // uniform branch
            x = recv[r * 3 + 0];
            y = recv[r * 3 + 1];
            z = recv[r * 3 + 2];
        }
        rx[c]  = rfl_f(x);
        ry[c]  = rfl_f(y);
        rz[c]  = rfl_f(z);
        rsq[c] = rfl_f((x * x + y * y) + z * z);   // no FMA (pragma)
    }

    float best[RPW];
    int   bidx[RPW];
#pragma unroll
    for (int c = 0; c < RPW; ++c) { best[c] = FLT_MAX; bidx[c] = 0x7fffffff; }

    // one pair-eval against all 16 receivers (pure VALU, 8 ops/pair)
    auto eval_point = [&](float x, float y, float z, int gidx) {
        const float ms = (x * x + y * y) + z * z;   // matches jnp.sum(m*m): no FMA
#pragma unroll
        for (int c = 0; c < RPW; ++c) {
            float cr = fmaf(rz[c], z, fmaf(ry[c], y, rx[c] * x));  // Eigen K-asc
            float d2 = fmaf(-2.0f, cr, ms) + rsq[c];
            if (d2 < best[c]) { best[c] = d2; bidx[c] = gidx; }    // strict <
        }
    };

    const bool writer = (rq == 0);           // dedicated writer quarter (r3 pattern)
    const int  H    = (ntiles + NHALF - 1) / NHALF;
    const int  tEnd = ((hf + 1) * H < ntiles) ? (hf + 1) * H : ntiles;

    for (int t = hf * H + q0; t < tEnd; t += NPHASE) {
        const int p0 = (t << 10) + (wave << 8) + (lane << 2);   // lane's 4 points
        if (p0 + 4 <= L) {
            const float4* __restrict__ m4 = (const float4*)(mesh + (size_t)p0 * 3);
            const float4 fa = m4[0], fb = m4[1], fc = m4[2];
            if (writer) {
                float4* __restrict__ o4 = (float4*)(out + (size_t)p0 * 4);
                o4[0] = make_float4(fa.x, fa.y, fa.z, 0.f);
                o4[1] = make_float4(fa.w, fb.x, fb.y, 0.f);
                o4[2] = make_float4(fb.z, fb.w, fc.x, 0.f);
                o4[3] = make_float4(fc.y, fc.z, fc.w, 0.f);
            }
            eval_point(fa.x, fa.y, fa.z, p0 + 0);
            eval_point(fa.w, fb.x, fb.y, p0 + 1);
            eval_point(fb.z, fb.w, fc.x, p0 + 2);
            eval_point(fc.y, fc.z, fc.w, p0 + 3);
        } else {
            for (int j = 0; j < 4; ++j) {
                const int p = p0 + j;
                if (p >= L) break;
                const float x = mesh[(size_t)p * 3 + 0];
                const float y = mesh[(size_t)p * 3 + 1];
                const float z = mesh[(size_t)p * 3 + 2];
                if (writer) {
                    out[(size_t)p * 4 + 0] = x;
                    out[(size_t)p * 4 + 1] = y;
                    out[(size_t)p * 4 + 2] = z;
                    out[(size_t)p * 4 + 3] = 0.f;
                }
                eval_point(x, y, z, p);
            }
        }
    }

    // ---- per-wave butterfly reduce on packed (key|idx), then tiny LDS fold ----
#pragma unroll
    for (int c = 0; c < RPW; ++c) {
        unsigned long long kk =
            ((unsigned long long)monotone_key(best[c]) << 32) | (unsigned int)bidx[c];
#pragma unroll
        for (int off = 32; off >= 1; off >>= 1) {
            unsigned long long o = shfl_xor_u64(kk, off);
            if (o < kk) kk = o;
        }
        if (lane == 0) wmin[wave][c] = kk;
    }
    __syncthreads();
    if (tid < RPW) {
        unsigned long long kk = wmin[0][tid];
#pragma unroll
        for (int w = 1; w < 4; ++w) {
            unsigned long long o = wmin[w][tid];
            if (o < kk) kk = o;
        }
        const int r = rq * RPW + tid;
        if (r < B) atomicMin(&ws[r], kk);
    }
}

// scatter one-hot 1.0s and emit closest_points
__global__ void finalize_kernel(
        const float* __restrict__ mesh, const unsigned long long* __restrict__ ws,
        float* __restrict__ out, int L, int B) {
    const int r = threadIdx.x;
    if (r >= B) return;
    const int idx = (int)(ws[r] & 0xFFFFFFFFull);
    out[(size_t)idx * 4 + 3] = 1.0f;
    float* cp = out + (size_t)L * 4 + (size_t)r * 3;
    cp[0] = mesh[(size_t)idx * 3 + 0];
    cp[1] = mesh[(size_t)idx * 3 + 1];
    cp[2] = mesh[(size_t)idx * 3 + 2];
}

extern "C" void kernel_launch(void* const* d_in, const int* in_sizes, int n_in,
                              void* d_out, int out_size, void* d_ws, size_t ws_size,
                              hipStream_t stream) {
    const float* mesh = (const float*)d_in[0];
    const float* recv = (const float*)d_in[1];
    float* out = (float*)d_out;
    const int L = in_sizes[0] / 3;
    const int B = in_sizes[1] / 3;   // 64
    unsigned long long* ws = (unsigned long long*)d_ws;

    // init per-receiver packed (key|idx) mins to all-ones (max)
    hipMemsetAsync(ws, 0xFF, (size_t)B * sizeof(unsigned long long), stream);

    const int ntiles = (L + 1023) / 1024;
    fused_kernel<<<4 * NHALF * NPHASE, 256, 0, stream>>>(mesh, recv, out, ws, L, B, ntiles);

    finalize_kernel<<<1, 64, 0, stream>>>(mesh, ws, out, L, B);
}

// Round 7
// 68.366 us; speedup vs baseline: 2.1625x; 1.2799x over previous
//
#include <hip/hip_runtime.h>
#include <cfloat>
#include <math.h>
#include <stdint.h>

// Match XLA-CPU f32 arithmetic exactly: no implicit contraction anywhere;
// FMA only where written explicitly (Eigen-gemm-style cross product).
#pragma clang fp contract(off)

#define RPW 16    // receivers per block (quarter of B=64)
#define NQ  256   // tile phases; grid = 4*NQ = 1024 (r3 geometry: best. r5/r6
                  // showed bigger grids enlarge L2 working set and regress.)

__device__ __forceinline__ uint32_t monotone_key(float f) {
    uint32_t u = __float_as_uint(f);
    return (u & 0x80000000u) ? ~u : (u | 0x80000000u);
}

// force a wave-uniform float into an SGPR
__device__ __forceinline__ float rfl_f(float x) {
    return __uint_as_float((uint32_t)__builtin_amdgcn_readfirstlane((int)__float_as_uint(x)));
}

__device__ __forceinline__ unsigned long long shfl_xor_u64(unsigned long long v, int m) {
    uint32_t lo = (uint32_t)v, hi = (uint32_t)(v >> 32);
    lo = (uint32_t)__shfl_xor((int)lo, m, 64);
    hi = (uint32_t)__shfl_xor((int)hi, m, 64);
    return ((unsigned long long)hi << 32) | lo;
}

// lane = point; 16 receivers in SGPRs -> pure-VALU inner loop.
// Min-fold: per (tile, receiver) fold the lane's 4 d2 via v_min (value only),
// track the winning GROUP (p0>>2) with one strict compare; exact index is
// recovered in finalize by re-evaluating the 4-point group bit-identically.
// Group ordering argument: groups partition index space ascending with p0,
// so the lowest-p0 group attaining the global min d2 contains the reference's
// first-occurrence argmin; u64 min on (mono(d2)<<32 | p0>>2) picks exactly it.
// launch_bounds(256,4): cap 128 VGPRs — do NOT squeeze the allocator (r4:
// (256,8) forced VGPR=32 and spilled best[]/grp[] to scratch, +600MB HBM).
__global__ void __launch_bounds__(256, 4) fused_kernel(
        const float* __restrict__ mesh, const float* __restrict__ recv,
        float* __restrict__ out, unsigned long long* __restrict__ ws,
        int L, int B, int ntiles) {
    __shared__ unsigned long long wmin[4][RPW];

    const int tid  = threadIdx.x;
    const int lane = tid & 63;
    const int wave = tid >> 6;
    const int rq   = blockIdx.x / NQ;      // receiver quarter 0..3
    const int q0   = blockIdx.x % NQ;      // starting tile phase

    // ---- receiver set into SGPRs (once) ----
    float rx[RPW], ry[RPW], rz[RPW], rsq[RPW];
#pragma unroll
    for (int c = 0; c < RPW; ++c) {
        const int r = rq * RPW + c;
        float x = 0.f, y = 0.f, z = 0.f;
        if (r < B) {                       // uniform branch
            x = recv[r * 3 + 0];
            y = recv[r * 3 + 1];
            z = recv[r * 3 + 2];
        }
        rx[c]  = rfl_f(x);
        ry[c]  = rfl_f(y);
        rz[c]  = rfl_f(z);
        rsq[c] = rfl_f((x * x + y * y) + z * z);   // no FMA (pragma)
    }

    float    best[RPW];
    uint32_t grp[RPW];
#pragma unroll
    for (int c = 0; c < RPW; ++c) { best[c] = FLT_MAX; grp[c] = 0; }

    const bool writer = (rq == 0);         // dedicated writer quarter (r3 pattern)

    for (int t = q0; t < ntiles; t += NQ) {
        const int p0 = (t << 10) + (wave << 8) + (lane << 2);   // lane's 4 points
        float x0, y0, z0, x1, y1, z1, x2, y2, z2, x3, y3, z3;
        float ms0, ms1, ms2, ms3;
        if (p0 + 4 <= L) {
            const float4* __restrict__ m4 = (const float4*)(mesh + (size_t)p0 * 3);
            const float4 fa = m4[0], fb = m4[1], fc = m4[2];
            if (writer) {
                float4* __restrict__ o4 = (float4*)(out + (size_t)p0 * 4);
                o4[0] = make_float4(fa.x, fa.y, fa.z, 0.f);
                o4[1] = make_float4(fa.w, fb.x, fb.y, 0.f);
                o4[2] = make_float4(fb.z, fb.w, fc.x, 0.f);
                o4[3] = make_float4(fc.y, fc.z, fc.w, 0.f);
            }
            x0 = fa.x; y0 = fa.y; z0 = fa.z;
            x1 = fa.w; y1 = fb.x; z1 = fb.y;
            x2 = fb.z; y2 = fb.w; z2 = fc.x;
            x3 = fc.y; y3 = fc.z; z3 = fc.w;
            ms0 = (x0 * x0 + y0 * y0) + z0 * z0;   // matches jnp.sum(m*m): no FMA
            ms1 = (x1 * x1 + y1 * y1) + z1 * z1;
            ms2 = (x2 * x2 + y2 * y2) + z2 * z2;
            ms3 = (x3 * x3 + y3 * y3) + z3 * z3;
        } else {
            float xs[4], ys[4], zs[4], mss[4];
            for (int j = 0; j < 4; ++j) {
                const int p = p0 + j;
                if (p < L) {
                    xs[j] = mesh[(size_t)p * 3 + 0];
                    ys[j] = mesh[(size_t)p * 3 + 1];
                    zs[j] = mesh[(size_t)p * 3 + 2];
                    mss[j] = (xs[j] * xs[j] + ys[j] * ys[j]) + zs[j] * zs[j];
                    if (writer) {
                        out[(size_t)p * 4 + 0] = xs[j];
                        out[(size_t)p * 4 + 1] = ys[j];
                        out[(size_t)p * 4 + 2] = zs[j];
                        out[(size_t)p * 4 + 3] = 0.f;
                    }
                } else {
                    xs[j] = 0.f; ys[j] = 0.f; zs[j] = 0.f;
                    mss[j] = INFINITY;     // d2 = +inf, never selected
                }
            }
            x0 = xs[0]; y0 = ys[0]; z0 = zs[0]; ms0 = mss[0];
            x1 = xs[1]; y1 = ys[1]; z1 = zs[1]; ms1 = mss[1];
            x2 = xs[2]; y2 = ys[2]; z2 = zs[2]; ms2 = mss[2];
            x3 = xs[3]; y3 = ys[3]; z3 = zs[3]; ms3 = mss[3];
        }

        const uint32_t g = (uint32_t)p0 >> 2;   // group id, same for all c
#pragma unroll
        for (int c = 0; c < RPW; ++c) {
            // Eigen gemm K-ascending FMA chain; d2 = fma(-2,cr,ms) + rsq
            float cr0 = fmaf(rz[c], z0, fmaf(ry[c], y0, rx[c] * x0));
            float d0  = fmaf(-2.0f, cr0, ms0) + rsq[c];
            float cr1 = fmaf(rz[c], z1, fmaf(ry[c], y1, rx[c] * x1));
            float d1  = fmaf(-2.0f, cr1, ms1) + rsq[c];
            float cr2 = fmaf(rz[c], z2, fmaf(ry[c], y2, rx[c] * x2));
            float d2v = fmaf(-2.0f, cr2, ms2) + rsq[c];
            float cr3 = fmaf(rz[c], z3, fmaf(ry[c], y3, rx[c] * x3));
            float d3  = fmaf(-2.0f, cr3, ms3) + rsq[c];
            // value-only fold (v_min3 + v_min); ties in VALUE are identical
            // bits, index ties resolved by group ordering + finalize re-eval
            float tl = fminf(fminf(fminf(d0, d1), d2v), d3);
            if (tl < best[c]) { best[c] = tl; grp[c] = g; }   // strict <
        }
    }

    // ---- per-wave butterfly reduce on packed (key|group), tiny LDS fold ----
#pragma unroll
    for (int c = 0; c < RPW; ++c) {
        unsigned long long kk =
            ((unsigned long long)monotone_key(best[c]) << 32) | grp[c];
#pragma unroll
        for (int off = 32; off >= 1; off >>= 1) {
            unsigned long long o = shfl_xor_u64(kk, off);
            if (o < kk) kk = o;
        }
        if (lane == 0) wmin[wave][c] = kk;
    }
    __syncthreads();
    if (tid < RPW) {
        unsigned long long kk = wmin[0][tid];
#pragma unroll
        for (int w = 1; w < 4; ++w) {
            unsigned long long o = wmin[w][tid];
            if (o < kk) kk = o;
        }
        const int r = rq * RPW + tid;
        if (r < B) atomicMin(&ws[r], kk);
    }
}

// Recover exact argmin within the winning 4-point group (bit-identical
// re-evaluation, same TU => same contract-off arithmetic), then scatter
// one-hot 1.0 and emit closest_points.
__global__ void finalize_kernel(
        const float* __restrict__ mesh, const float* __restrict__ recv,
        const unsigned long long* __restrict__ ws,
        float* __restrict__ out, int L, int B) {
    const int r = threadIdx.x;
    if (r >= B) return;
    const unsigned long long key = ws[r];
    const int p0 = (int)(key & 0xFFFFFFFFull) << 2;

    const float rx = recv[r * 3 + 0];
    const float ry = recv[r * 3 + 1];
    const float rz = recv[r * 3 + 2];
    const float rsq = (rx * rx + ry * ry) + rz * rz;   // no FMA (pragma)

    float bestd = FLT_MAX;
    int   bidx  = p0;
    for (int j = 0; j < 4; ++j) {
        const int p = p0 + j;
        float d2;
        if (p < L) {
            const float x = mesh[(size_t)p * 3 + 0];
            const float y = mesh[(size_t)p * 3 + 1];
            const float z = mesh[(size_t)p * 3 + 2];
            const float ms = (x * x + y * y) + z * z;
            const float cr = fmaf(rz, z, fmaf(ry, y, rx * x));
            d2 = fmaf(-2.0f, cr, ms) + rsq;
        } else {
            d2 = INFINITY;
        }
        if (d2 < bestd) { bestd = d2; bidx = p; }   // strict <: first index
    }

    out[(size_t)bidx * 4 + 3] = 1.0f;
    float* cp = out + (size_t)L * 4 + (size_t)r * 3;
    cp[0] = mesh[(size_t)bidx * 3 + 0];
    cp[1] = mesh[(size_t)bidx * 3 + 1];
    cp[2] = mesh[(size_t)bidx * 3 + 2];
}

extern "C" void kernel_launch(void* const* d_in, const int* in_sizes, int n_in,
                              void* d_out, int out_size, void* d_ws, size_t ws_size,
                              hipStream_t stream) {
    const float* mesh = (const float*)d_in[0];
    const float* recv = (const float*)d_in[1];
    float* out = (float*)d_out;
    const int L = in_sizes[0] / 3;
    const int B = in_sizes[1] / 3;   // 64
    unsigned long long* ws = (unsigned long long*)d_ws;

    // init per-receiver packed (key|group) mins to all-ones (max)
    hipMemsetAsync(ws, 0xFF, (size_t)B * sizeof(unsigned long long), stream);

    const int ntiles = (L + 1023) / 1024;
    fused_kernel<<<4 * NQ, 256, 0, stream>>>(mesh, recv, out, ws, L, B, ntiles);

    finalize_kernel<<<1, 64, 0, stream>>>(mesh, recv, ws, out, L, B);
}